// Round 12
// baseline (7407.004 us; speedup 1.0000x reference)
//
#include <hip/hip_runtime.h>
#include <cmath>
#include <cstdint>
#include <cfloat>

// ---------------------------------------------------------------------------
// CenterNet head, MI355X. Round 12: 32-wide oc-tile convs (2x FLOP per
// staged chunk -> halves barrier/drain tax per FLOP). Rest frozen R10/R11.
// Numerics contract (proven R3-R11, absmax 0.0):
//   - cls 3x3 convs: f32 fmaf chains, EXACT per-output order (ci asc, kh, kw).
//   - cls 1x1: f64 accum (ci 0..127) -> correctly-rounded f32 logits.
//   - Selection on f32 logits, ties by lowest index (u64 key = ordf<<32 | ~i).
//   - wh: sparse f32 recompute at selected pixels (tolerance 10.08).
// ---------------------------------------------------------------------------

#define CN_B   16
#define CN_H   128
#define CN_W   128
#define CN_HW  16384
#define CN_CLS 80
#define CN_K   100
#define NEG_SENT (-3.402823466e+38f)

__device__ __forceinline__ unsigned ordf(float v) {
    unsigned b = __float_as_uint(v);
    return (b >> 31) ? ~b : (b | 0x80000000u);
}
__device__ __forceinline__ float unordf(unsigned o) {
    return __uint_as_float((o >> 31) ? (o & 0x7fffffffu) : ~o);
}

// Bijective chunked XCD transform (m204): XCD x gets a contiguous chunk.
__device__ __forceinline__ int xcd_swz(int bid, int nwg) {
    const int q = nwg >> 3, r = nwg & 7;
    const int x = bid & 7, off = bid >> 3;
    return (x < r ? x * (q + 1) : r * (q + 1) + (x - r) * q) + off;
}

// ---------------------------------------------------------------------------
// 3x3 weight transpose (bit-copy): wt[(ci*9+tap)*CO + co] = w[co][ci][tap].
// ---------------------------------------------------------------------------
__global__ __launch_bounds__(256) void wtr_k(
    const float* __restrict__ w, float* __restrict__ wt, int CI, int CO)
{
    const int e = blockIdx.x * 256 + threadIdx.x;
    const int n = CI * 9 * CO;
    if (e < n) {
        const int co = e % CO;
        const int rest = e / CO;            // ci*9 + tap
        wt[e] = w[(size_t)co * CI * 9 + rest];
    }
}

// 1x1 weight transpose to f64 (exact): wt[ci*80 + o] = (double)w[o*128 + ci].
__global__ __launch_bounds__(256) void wtr1x1_k(
    const float* __restrict__ w, double* __restrict__ wt)
{
    const int e = blockIdx.x * 256 + threadIdx.x;
    if (e < 128 * CN_CLS) {
        const int ci = e / CN_CLS, o = e % CN_CLS;
        wt[e] = (double)w[(size_t)o * 128 + ci];
    }
}

// ---------------------------------------------------------------------------
// f32 3x3 conv, pad 1, bias + ReLU. Tile: 8 rows x 128 cols x 32 oc, CC=4,
// SGPR weights, contiguous-row px mapping (thread r2 owns rows r2*4..r2*4+3).
// 32-oc tile: each staged chunk feeds 9216 FMAs/thread (2x R11) -> the
// per-chunk barrier+drain tax halves per FLOP.
// Per-(row,o) fmaf chain: (ci0 asc, cc, kh, kw) — IDENTICAL bits to R3-R11
// (oc-tile widening is a pure permutation of block->output mapping).
// grid.x = Bc * 16 * (CO/32), co-tile fastest + XCD swizzle.
// ---------------------------------------------------------------------------
template<int CI>
__device__ __forceinline__ void conv3x3_body(
    const float* __restrict__ in, const float* __restrict__ wt,
    const float* __restrict__ bias, float* __restrict__ out, int CO)
{
    constexpr int CC = 4;
    const int wg  = xcd_swz(blockIdx.x, gridDim.x);
    const int cob = CO >> 5;
    const int co0 = (wg % cob) * 32;
    const int tmp = wg / cob;
    const int h0  = (tmp & 15) * 8;
    const int b   = tmp >> 4;

    __shared__ float lin[CC][10][132];   // 21.1 KB

    const int t   = threadIdx.x;
    const int col = t & 127;
    const int r2  = t >> 7;              // 0..1: rows r2*4 .. r2*4+3
    const int g   = t >> 6;              // staging cc 0..3
    const int ln  = t & 63;

    float acc[4][32];
#pragma unroll
    for (int j = 0; j < 4; ++j)
#pragma unroll
        for (int o = 0; o < 32; ++o) acc[j][o] = 0.f;

    for (int ci0 = 0; ci0 < CI; ci0 += CC) {
        // ---- input staging (proven R5/R8 form) ----
        {
            const float* base = in + (((size_t)b * CI + ci0 + g) * CN_H) * CN_W;
#pragma unroll
            for (int rr = 0; rr < 10; ++rr) {
                const int srow = h0 - 1 + rr;
                const bool rok = (unsigned)srow < (unsigned)CN_H;
                const float* src = base + srow * CN_W;
#pragma unroll
                for (int q = 0; q < 2; ++q) {
                    const int lidx = ln + 64 * q;
                    const int scol = lidx - 1;
                    lin[g][rr][lidx] =
                        (rok && (unsigned)scol < (unsigned)CN_W) ? src[scol] : 0.f;
                }
                if (ln < 2) {
                    const int lidx = 128 + ln;
                    const int scol = lidx - 1;
                    lin[g][rr][lidx] =
                        (rok && (unsigned)scol < (unsigned)CN_W) ? src[scol] : 0.f;
                }
            }
        }
        __syncthreads();
        // ---- compute: 18 LDS reads/cc into registers, SGPR weights ----
        for (int cc = 0; cc < CC; ++cc) {
            float rb[6][3];
#pragma unroll
            for (int rr = 0; rr < 6; ++rr) {
                const int lr = r2 * 4 + rr;
                rb[rr][0] = lin[cc][lr][col + 0];
                rb[rr][1] = lin[cc][lr][col + 1];
                rb[rr][2] = lin[cc][lr][col + 2];
            }
#pragma unroll
            for (int kh = 0; kh < 3; ++kh) {
#pragma unroll
                for (int kw = 0; kw < 3; ++kw) {
                    const float* wr =
                        wt + (size_t)((ci0 + cc) * 9 + kh * 3 + kw) * CO + co0;
#pragma unroll
                    for (int o = 0; o < 32; ++o) {
                        const float w = wr[o];      // wave-uniform -> s_load
                        acc[0][o] = fmaf(rb[0 + kh][kw], w, acc[0][o]);
                        acc[1][o] = fmaf(rb[1 + kh][kw], w, acc[1][o]);
                        acc[2][o] = fmaf(rb[2 + kh][kw], w, acc[2][o]);
                        acc[3][o] = fmaf(rb[3 + kh][kw], w, acc[3][o]);
                    }
                }
            }
        }
        __syncthreads();
    }

#pragma unroll
    for (int j = 0; j < 4; ++j) {
        const int h = h0 + r2 * 4 + j;
#pragma unroll
        for (int o = 0; o < 32; ++o) {
            float v = acc[j][o] + bias[co0 + o];
            v = v > 0.f ? v : 0.f;
            out[(((size_t)b * CO + co0 + o) * CN_H + h) * CN_W + col] = v;
        }
    }
}

__global__ __launch_bounds__(256) void conv_a_k(   // cls1: 64 -> 128
    const float* __restrict__ in, const float* __restrict__ wt,
    const float* __restrict__ bias, float* __restrict__ out, int CO)
{ conv3x3_body<64>(in, wt, bias, out, CO); }

__global__ __launch_bounds__(256) void conv_b_k(   // cls2: 128 -> 128
    const float* __restrict__ in, const float* __restrict__ wt,
    const float* __restrict__ bias, float* __restrict__ out, int CO)
{ conv3x3_body<128>(in, wt, bias, out, CO); }

// ---------------------------------------------------------------------------
// 1x1 cls: 128 -> 80, f64 accumulate, SGPR weight path (proven R10).
// ---------------------------------------------------------------------------
__global__ __launch_bounds__(256) void conv1x1_cls_k(
    const float* __restrict__ h2, const double* __restrict__ wt,
    const float* __restrict__ bias, float* __restrict__ logits)
{
    constexpr int CI = 128;
    const int wg = xcd_swz(blockIdx.x, gridDim.x);
    const int og = wg % 5;
    const int pb = wg / 5;
    const int b  = pb / 64;
    const int p  = (pb % 64) * 256 + threadIdx.x;
    const int o0 = og * 16;

    double acc[16];
#pragma unroll
    for (int o = 0; o < 16; ++o) acc[o] = 0.0;

    for (int ci = 0; ci < CI; ++ci) {
        const double v = (double)h2[((size_t)b * CI + ci) * CN_HW + p];
        const double* wr = wt + (size_t)ci * CN_CLS + o0;   // wave-uniform
#pragma unroll
        for (int o = 0; o < 16; ++o) acc[o] = fma(v, wr[o], acc[o]);
    }
#pragma unroll
    for (int o = 0; o < 16; ++o)
        logits[((size_t)b * CN_CLS + o0 + o) * CN_HW + p] =
            (float)(acc[o] + (double)bias[o0 + o]);
}

// ---------------------------------------------------------------------------
// NMS + per-class top-100 (exact R9-R11 body: global-read flags, low LDS).
// ---------------------------------------------------------------------------
#define NMS_CAP 2048

__global__ __launch_bounds__(256) void nms_topk_k(
    const float* __restrict__ logits,
    float* __restrict__ pc_logit, int* __restrict__ pc_ind, int b0)
{
    __shared__ unsigned long long cand[NMS_CAP];
    __shared__ int   cnt;
    __shared__ float rv[4];
    __shared__ int   ri[4];
    __shared__ int   pick;

    const int bc = blockIdx.x;
    const int bl = bc / CN_CLS;
    const int c  = bc % CN_CLS;
    const int bg = b0 + bl;
    const int t  = threadIdx.x;
    const float* L = logits + (size_t)bc * CN_HW;

    if (t == 0) cnt = 0;
    __syncthreads();

    unsigned long long flags = 0;
    for (int k = 0; k < 64; ++k) {
        const int p   = t + 256 * k;
        const int row = p >> 7, cl = p & 127;
        const float c0 = L[p];
        bool mx = true;
#pragma unroll
        for (int dr = -1; dr <= 1; ++dr)
#pragma unroll
            for (int dc = -1; dc <= 1; ++dc) {
                if (dr == 0 && dc == 0) continue;
                int rr = row + dr, cc2 = cl + dc;
                if ((unsigned)rr < (unsigned)CN_H && (unsigned)cc2 < (unsigned)CN_W)
                    if (L[(rr << 7) + cc2] > c0) mx = false;
            }
        if (mx) flags |= 1ull << k;
    }

    {
        unsigned long long f = flags;
        while (f) {
            int k = __ffsll((long long)f) - 1;
            f &= f - 1;
            const int p = t + 256 * k;
            const int slot = atomicAdd(&cnt, 1);
            if (slot < NMS_CAP)
                cand[slot] = ((unsigned long long)ordf(L[p]) << 32) | (unsigned)(~p);
        }
    }
    __syncthreads();
    const int M = cnt;

    if (M >= CN_K && M <= NMS_CAP) {
        int P = 128;
        while (P < M) P <<= 1;
        for (int i = M + t; i < P; i += 256) cand[i] = 0ull;
        __syncthreads();
        for (int k = 2; k <= P; k <<= 1) {
            for (int j = k >> 1; j > 0; j >>= 1) {
                for (int n = t; n < (P >> 1); n += 256) {
                    const int i = ((n & ~(j - 1)) << 1) | (n & (j - 1));
                    const int m = i | j;
                    const unsigned long long a = cand[i], bqq = cand[m];
                    const bool up = ((i & k) == 0);
                    if (up ? (a < bqq) : (a > bqq)) { cand[i] = bqq; cand[m] = a; }
                }
                __syncthreads();
            }
        }
        if (t < CN_K) {
            const unsigned long long key = cand[t];
            const int p = (int)(~(unsigned)key) & 0xFFFF;
            pc_logit[(size_t)bg * 8000 + c * CN_K + t] = unordf((unsigned)(key >> 32));
            pc_ind  [(size_t)bg * 8000 + c * CN_K + t] = p;
        }
    } else {
        unsigned long long removed = 0;
        for (int it = 0; it < CN_K; ++it) {
            float bv = -INFINITY;
            int   bi = 0x7fffffff;
            for (int k = 0; k < 64; ++k) {
                if ((removed >> k) & 1) continue;
                const int p = t + 256 * k;
                const float v = ((flags >> k) & 1) ? L[p] : NEG_SENT;
                if (v > bv || (v == bv && p < bi)) { bv = v; bi = p; }
            }
#pragma unroll
            for (int off = 32; off; off >>= 1) {
                float ov = __shfl_down(bv, off);
                int   oi = __shfl_down(bi, off);
                if (ov > bv || (ov == bv && oi < bi)) { bv = ov; bi = oi; }
            }
            const int wid = t >> 6;
            if ((t & 63) == 0) { rv[wid] = bv; ri[wid] = bi; }
            __syncthreads();
            if (t == 0) {
                for (int wv = 1; wv < 4; ++wv)
                    if (rv[wv] > bv || (rv[wv] == bv && ri[wv] < bi)) { bv = rv[wv]; bi = ri[wv]; }
                pc_logit[(size_t)bg * 8000 + c * CN_K + it] = bv;
                pc_ind  [(size_t)bg * 8000 + c * CN_K + it] = bi;
                pick = bi;
            }
            __syncthreads();
            const int pk = pick;
            if ((pk & 255) == t) removed |= 1ull << (pk >> 8);
            __syncthreads();
        }
    }
}

// ---------------------------------------------------------------------------
// Global top-100 via 80-way merge-pop (proven R10/R11).
// ---------------------------------------------------------------------------
__global__ __launch_bounds__(256) void global_topk_k(
    const float* __restrict__ pc_logit, const int* __restrict__ pc_ind,
    int* __restrict__ sel)
{
    constexpr int N = CN_CLS * CN_K;           // 8000
    __shared__ unsigned long long keys[N];     // 64 KB
    __shared__ unsigned long long heads[128];
    __shared__ int rcs[CN_CLS];

    const int b = blockIdx.x;
    const int t = threadIdx.x;

    for (int n = t; n < N; n += 256) {
        const float v = pc_logit[(size_t)b * N + n];
        keys[n] = ((unsigned long long)ordf(v) << 32) | (unsigned)(~n);
    }
    if (t >= CN_CLS && t < 128) heads[t] = 0ull;
    __syncthreads();
    if (t < CN_CLS) { heads[t] = keys[t * CN_K]; rcs[t] = 1; }
    __syncthreads();

    for (int it = 0; it < CN_K; ++it) {
        if (t < 64) {
            unsigned long long k0 = heads[t];
            unsigned long long k1 = heads[t + 64];
            unsigned long long bk = (k0 >= k1) ? k0 : k1;
#pragma unroll
            for (int off = 32; off; off >>= 1) {
                unsigned long long ok = __shfl_down(bk, off);
                if (ok > bk) bk = ok;
            }
            if (t == 0) {
                const int flat = (int)(~(unsigned)bk);
                const int c    = flat / CN_K;
                sel[((size_t)b * CN_K + it) * 3 + 0] = pc_ind[(size_t)b * N + flat];
                sel[((size_t)b * CN_K + it) * 3 + 1] = c;
                sel[((size_t)b * CN_K + it) * 3 + 2] = (int)(unsigned)(bk >> 32);
                const int rc = rcs[c]++;
                heads[c] = (rc < CN_K) ? keys[c * CN_K + rc] : 0ull;
            }
        }
        __syncthreads();
    }
}

// ---------------------------------------------------------------------------
// Sparse wh + bbox assembly (proven R8-R11): one block per (b, k).
// ---------------------------------------------------------------------------
__global__ __launch_bounds__(256) void whbbox_k(
    const float* __restrict__ x,
    const float* __restrict__ w1, const float* __restrict__ b1,
    const float* __restrict__ w2, const float* __restrict__ b2,
    const float* __restrict__ w3, const float* __restrict__ b3,
    const int* __restrict__ sel, float* __restrict__ out)
{
    __shared__ float xw[64][25];
    __shared__ float g1s[9][64];
    __shared__ float g2s[64];
    __shared__ float whs[4];

    const int bk = blockIdx.x;
    const int b  = bk / CN_K;
    const int k  = bk % CN_K;
    const int t  = threadIdx.x;

    const int   ind   = sel[((size_t)b * CN_K + k) * 3 + 0];
    const int   cls   = sel[((size_t)b * CN_K + k) * 3 + 1];
    const float lg    = unordf((unsigned)sel[((size_t)b * CN_K + k) * 3 + 2]);
    const int   py = ind >> 7, px = ind & 127;

    for (int e = t; e < 64 * 25; e += 256) {
        const int c = e / 25, r = e % 25;
        const int qy = py + r / 5 - 2, qx = px + r % 5 - 2;
        float v = 0.f;
        if ((unsigned)qy < (unsigned)CN_H && (unsigned)qx < (unsigned)CN_W)
            v = x[(((size_t)b * 64 + c) * CN_H + qy) * CN_W + qx];
        xw[c][r] = v;
    }
    __syncthreads();

    for (int e = t; e < 576; e += 256) {
        const int ci = e & 63, qp = e >> 6;
        const int qdy = qp / 3 - 1, qdx = qp % 3 - 1;
        const int qy = py + qdy, qx = px + qdx;
        float s = 0.f;
        if ((unsigned)qy < (unsigned)CN_H && (unsigned)qx < (unsigned)CN_W) {
            const float* wp = w1 + (size_t)ci * 64 * 9;
            for (int cj = 0; cj < 64; ++cj) {
#pragma unroll
                for (int jh = 0; jh < 3; ++jh)
#pragma unroll
                    for (int jw = 0; jw < 3; ++jw)
                        s = fmaf(xw[cj][(qdy + jh + 1) * 5 + (qdx + jw + 1)],
                                 wp[cj * 9 + jh * 3 + jw], s);
            }
            s += b1[ci];
            s = s > 0.f ? s : 0.f;
        }
        g1s[qp][ci] = s;
    }
    __syncthreads();

    if (t < 64) {
        const int oc = t;
        const float* wp = w2 + (size_t)oc * 64 * 9;
        float s = 0.f;
        for (int ci = 0; ci < 64; ++ci) {
#pragma unroll
            for (int kh = 0; kh < 3; ++kh)
#pragma unroll
                for (int kw = 0; kw < 3; ++kw)
                    s = fmaf(g1s[kh * 3 + kw][ci], wp[ci * 9 + kh * 3 + kw], s);
        }
        s += b2[oc];
        g2s[oc] = s > 0.f ? s : 0.f;
    }
    __syncthreads();

    if (t < 4) {
        float s = 0.f;
        const float* wp = w3 + (size_t)t * 64;
        for (int oc = 0; oc < 64; ++oc) s = fmaf(g2s[oc], wp[oc], s);
        s += b3[t];
        s = s > 0.f ? s : 0.f;
        whs[t] = s * 16.0f;
    }
    __syncthreads();

    if (t == 0) {
        const float score = (float)(1.0 / (1.0 + exp(-(double)lg)));
        const float ys = (float)py * 4.0f;
        const float xs = (float)px * 4.0f;
        float* row = out + ((size_t)b * CN_K + k) * 6;
        row[0] = xs - whs[0];
        row[1] = ys - whs[1];
        row[2] = xs + whs[2];
        row[3] = ys + whs[3];
        row[4] = score;
        row[5] = (float)cls;
        out[CN_B * CN_K * 6 + b * CN_K + k] = (score > 0.01f) ? 1.0f : 0.0f;
    }
}

// ---------------------------------------------------------------------------
extern "C" void kernel_launch(void* const* d_in, const int* in_sizes, int n_in,
                              void* d_out, int out_size, void* d_ws, size_t ws_size,
                              hipStream_t stream)
{
    (void)in_sizes; (void)n_in; (void)out_size;

    const float* x      = (const float*)d_in[0];
    const float* cls_w1 = (const float*)d_in[1];
    const float* cls_b1 = (const float*)d_in[2];
    const float* cls_w2 = (const float*)d_in[3];
    const float* cls_b2 = (const float*)d_in[4];
    const float* cls_w3 = (const float*)d_in[5];
    const float* cls_b3 = (const float*)d_in[6];
    const float* wh_w1  = (const float*)d_in[7];
    const float* wh_b1  = (const float*)d_in[8];
    const float* wh_w2  = (const float*)d_in[9];
    const float* wh_b2  = (const float*)d_in[10];
    const float* wh_w3  = (const float*)d_in[11];
    const float* wh_b3  = (const float*)d_in[12];
    float* out = (float*)d_out;

    const size_t SZ_PCS = 512000u, SZ_PCI = 512000u;
    const size_t SZ_WT1 = 294912u, SZ_WT2 = 589824u;
    const size_t SZ_WTC = 81920u;
    const size_t SZ_SEL = 19200u;
    const size_t PERS = SZ_PCS + SZ_PCI + SZ_WT1 + SZ_WT2 + SZ_WTC + SZ_SEL;
    const size_t PER_IMG = 16777216u;

    int Bc = 1;
    if (ws_size > PERS) {
        size_t m = (ws_size - PERS) / PER_IMG;
        Bc = (int)(m < 1 ? 1 : (m > 16 ? 16 : m));
    }

    char* ws = (char*)d_ws;
    float*  pc_s = (float*)ws;
    int*    pc_i = (int*)(ws + SZ_PCS);
    float*  wt1  = (float*)(ws + SZ_PCS + SZ_PCI);
    float*  wt2  = (float*)(ws + SZ_PCS + SZ_PCI + SZ_WT1);
    double* wtc  = (double*)(ws + SZ_PCS + SZ_PCI + SZ_WT1 + SZ_WT2);
    int*    sel  = (int*)(ws + SZ_PCS + SZ_PCI + SZ_WT1 + SZ_WT2 + SZ_WTC);
    char*   regA = ws + PERS;
    char*   regB = regA + (size_t)Bc * 8388608u;

    dim3 blk(256);

    wtr_k<<<dim3((64 * 9 * 128 + 255) / 256), blk, 0, stream>>>(cls_w1, wt1, 64, 128);
    wtr_k<<<dim3((128 * 9 * 128 + 255) / 256), blk, 0, stream>>>(cls_w2, wt2, 128, 128);
    wtr1x1_k<<<dim3((128 * CN_CLS + 255) / 256), blk, 0, stream>>>(cls_w3, wtc);

    for (int b0 = 0; b0 < CN_B; b0 += Bc) {
        const int Bcur = (CN_B - b0 < Bc) ? (CN_B - b0) : Bc;
        const float* xc = x + (size_t)b0 * 64 * CN_HW;
        float* h1     = (float*)regA;
        float* h2     = (float*)regB;
        float* logits = (float*)regA;

        conv_a_k<<<dim3(Bcur * 16 * 4), blk, 0, stream>>>(xc, wt1, cls_b1, h1, 128);
        conv_b_k<<<dim3(Bcur * 16 * 4), blk, 0, stream>>>(h1, wt2, cls_b2, h2, 128);
        conv1x1_cls_k<<<dim3(Bcur * 64 * 5), blk, 0, stream>>>(h2, wtc, cls_b3, logits);
        nms_topk_k<<<dim3(Bcur * CN_CLS), blk, 0, stream>>>(logits, pc_s, pc_i, b0);
    }

    global_topk_k<<<dim3(CN_B), blk, 0, stream>>>(pc_s, pc_i, sel);
    whbbox_k<<<dim3(CN_B * CN_K), blk, 0, stream>>>(
        x, wh_w1, wh_b1, wh_w2, wh_b2, wh_w3, wh_b3, sel, out);
}

// Round 13
// 2334.783 us; speedup vs baseline: 3.1725x; 3.1725x over previous
//
#include <hip/hip_runtime.h>
#include <cmath>
#include <cstdint>
#include <cfloat>

// ---------------------------------------------------------------------------
// CenterNet head, MI355X. Round 13: R11 convs restored (proven 877us), NMS
// rewritten as wave-rolling 3x3 stencil (68 loads/thread vs 576).
// Numerics contract (proven R3-R11, absmax 0.0):
//   - cls 3x3 convs: f32 fmaf chains, EXACT per-output order (ci asc, kh, kw).
//   - cls 1x1: f64 accum (ci 0..127) -> correctly-rounded f32 logits.
//   - Selection on f32 logits, ties by lowest index (u64 key = ordf<<32 | ~i).
//   - NMS flag: max3x3(incl center)==center  ==  no neighbor strictly greater.
//   - wh: sparse f32 recompute at selected pixels (tolerance 10.08).
// ---------------------------------------------------------------------------

#define CN_B   16
#define CN_H   128
#define CN_W   128
#define CN_HW  16384
#define CN_CLS 80
#define CN_K   100
#define NEG_SENT (-3.402823466e+38f)

__device__ __forceinline__ unsigned ordf(float v) {
    unsigned b = __float_as_uint(v);
    return (b >> 31) ? ~b : (b | 0x80000000u);
}
__device__ __forceinline__ float unordf(unsigned o) {
    return __uint_as_float((o >> 31) ? (o & 0x7fffffffu) : ~o);
}

// Bijective chunked XCD transform (m204): XCD x gets a contiguous chunk.
__device__ __forceinline__ int xcd_swz(int bid, int nwg) {
    const int q = nwg >> 3, r = nwg & 7;
    const int x = bid & 7, off = bid >> 3;
    return (x < r ? x * (q + 1) : r * (q + 1) + (x - r) * q) + off;
}

// ---------------------------------------------------------------------------
// 3x3 weight transpose (bit-copy): wt[(ci*9+tap)*CO + co] = w[co][ci][tap].
// ---------------------------------------------------------------------------
__global__ __launch_bounds__(256) void wtr_k(
    const float* __restrict__ w, float* __restrict__ wt, int CI, int CO)
{
    const int e = blockIdx.x * 256 + threadIdx.x;
    const int n = CI * 9 * CO;
    if (e < n) {
        const int co = e % CO;
        const int rest = e / CO;            // ci*9 + tap
        wt[e] = w[(size_t)co * CI * 9 + rest];
    }
}

// 1x1 weight transpose to f64 (exact): wt[ci*80 + o] = (double)w[o*128 + ci].
__global__ __launch_bounds__(256) void wtr1x1_k(
    const float* __restrict__ w, double* __restrict__ wt)
{
    const int e = blockIdx.x * 256 + threadIdx.x;
    if (e < 128 * CN_CLS) {
        const int ci = e / CN_CLS, o = e % CN_CLS;
        wt[e] = (double)w[(size_t)o * 128 + ci];
    }
}

// ---------------------------------------------------------------------------
// f32 3x3 conv, pad 1, bias + ReLU. EXACT R11 body (877us conv_b, VGPR 64):
// tile 8 rows x 128 cols x 16 oc, CC=4, SGPR weights, contiguous-row px map.
// Per-(row,o) fmaf chain: (ci0 asc, cc, kh, kw) — IDENTICAL bits to R3-R11.
// grid.x = Bc * 16 * (CO/16), co-tile fastest + XCD swizzle.
// ---------------------------------------------------------------------------
template<int CI>
__device__ __forceinline__ void conv3x3_body(
    const float* __restrict__ in, const float* __restrict__ wt,
    const float* __restrict__ bias, float* __restrict__ out, int CO)
{
    constexpr int CC = 4;
    const int wg  = xcd_swz(blockIdx.x, gridDim.x);
    const int cob = CO >> 4;
    const int co0 = (wg % cob) * 16;
    const int tmp = wg / cob;
    const int h0  = (tmp & 15) * 8;
    const int b   = tmp >> 4;

    __shared__ float lin[CC][10][132];   // 21.1 KB

    const int t   = threadIdx.x;
    const int col = t & 127;
    const int r2  = t >> 7;              // 0..1: rows r2*4 .. r2*4+3
    const int g   = t >> 6;              // staging cc 0..3
    const int ln  = t & 63;

    float acc[4][16];
#pragma unroll
    for (int j = 0; j < 4; ++j)
#pragma unroll
        for (int o = 0; o < 16; ++o) acc[j][o] = 0.f;

    for (int ci0 = 0; ci0 < CI; ci0 += CC) {
        // ---- input staging (proven R5/R8 form) ----
        {
            const float* base = in + (((size_t)b * CI + ci0 + g) * CN_H) * CN_W;
#pragma unroll
            for (int rr = 0; rr < 10; ++rr) {
                const int srow = h0 - 1 + rr;
                const bool rok = (unsigned)srow < (unsigned)CN_H;
                const float* src = base + srow * CN_W;
#pragma unroll
                for (int q = 0; q < 2; ++q) {
                    const int lidx = ln + 64 * q;
                    const int scol = lidx - 1;
                    lin[g][rr][lidx] =
                        (rok && (unsigned)scol < (unsigned)CN_W) ? src[scol] : 0.f;
                }
                if (ln < 2) {
                    const int lidx = 128 + ln;
                    const int scol = lidx - 1;
                    lin[g][rr][lidx] =
                        (rok && (unsigned)scol < (unsigned)CN_W) ? src[scol] : 0.f;
                }
            }
        }
        __syncthreads();
        // ---- compute: 18 LDS reads/cc into registers, SGPR weights ----
        for (int cc = 0; cc < CC; ++cc) {
            float rb[6][3];
#pragma unroll
            for (int rr = 0; rr < 6; ++rr) {
                const int lr = r2 * 4 + rr;
                rb[rr][0] = lin[cc][lr][col + 0];
                rb[rr][1] = lin[cc][lr][col + 1];
                rb[rr][2] = lin[cc][lr][col + 2];
            }
#pragma unroll
            for (int kh = 0; kh < 3; ++kh) {
#pragma unroll
                for (int kw = 0; kw < 3; ++kw) {
                    const float* wr =
                        wt + (size_t)((ci0 + cc) * 9 + kh * 3 + kw) * CO + co0;
#pragma unroll
                    for (int o = 0; o < 16; ++o) {
                        const float w = wr[o];      // wave-uniform -> s_load
                        acc[0][o] = fmaf(rb[0 + kh][kw], w, acc[0][o]);
                        acc[1][o] = fmaf(rb[1 + kh][kw], w, acc[1][o]);
                        acc[2][o] = fmaf(rb[2 + kh][kw], w, acc[2][o]);
                        acc[3][o] = fmaf(rb[3 + kh][kw], w, acc[3][o]);
                    }
                }
            }
        }
        __syncthreads();
    }

#pragma unroll
    for (int j = 0; j < 4; ++j) {
        const int h = h0 + r2 * 4 + j;
#pragma unroll
        for (int o = 0; o < 16; ++o) {
            float v = acc[j][o] + bias[co0 + o];
            v = v > 0.f ? v : 0.f;
            out[(((size_t)b * CO + co0 + o) * CN_H + h) * CN_W + col] = v;
        }
    }
}

__global__ __launch_bounds__(256) void conv_a_k(   // cls1: 64 -> 128
    const float* __restrict__ in, const float* __restrict__ wt,
    const float* __restrict__ bias, float* __restrict__ out, int CO)
{ conv3x3_body<64>(in, wt, bias, out, CO); }

__global__ __launch_bounds__(256) void conv_b_k(   // cls2: 128 -> 128
    const float* __restrict__ in, const float* __restrict__ wt,
    const float* __restrict__ bias, float* __restrict__ out, int CO)
{ conv3x3_body<128>(in, wt, bias, out, CO); }

// ---------------------------------------------------------------------------
// 1x1 cls: 128 -> 80, f64 accumulate, SGPR weight path (proven R10/R11).
// ---------------------------------------------------------------------------
__global__ __launch_bounds__(256) void conv1x1_cls_k(
    const float* __restrict__ h2, const double* __restrict__ wt,
    const float* __restrict__ bias, float* __restrict__ logits)
{
    constexpr int CI = 128;
    const int wg = xcd_swz(blockIdx.x, gridDim.x);
    const int og = wg % 5;
    const int pb = wg / 5;
    const int b  = pb / 64;
    const int p  = (pb % 64) * 256 + threadIdx.x;
    const int o0 = og * 16;

    double acc[16];
#pragma unroll
    for (int o = 0; o < 16; ++o) acc[o] = 0.0;

    for (int ci = 0; ci < CI; ++ci) {
        const double v = (double)h2[((size_t)b * CI + ci) * CN_HW + p];
        const double* wr = wt + (size_t)ci * CN_CLS + o0;   // wave-uniform
#pragma unroll
        for (int o = 0; o < 16; ++o) acc[o] = fma(v, wr[o], acc[o]);
    }
#pragma unroll
    for (int o = 0; o < 16; ++o)
        logits[((size_t)b * CN_CLS + o0 + o) * CN_HW + p] =
            (float)(acc[o] + (double)bias[o0 + o]);
}

// ---------------------------------------------------------------------------
// NMS + per-class top-100. NEW scan: wave-rolling 3x3 stencil.
// Wave wv owns rows [wv*32, wv*32+32); lane ln owns cols {2ln, 2ln+1}.
// Per row: one float2 load + 2 shuffles; 3-row max window in registers.
// Flag: max3x3(incl center) == center  (== reference hmax==heat; borders
// -inf == reduce_window padding). Candidates -> atomic slots -> bitonic sort
// of (ordf(logit)<<32 | ~index) keys (proven). Fallback (M<100 or M>2048):
// R4-proven iterative argmax with old-style flags (never triggers in practice).
// ---------------------------------------------------------------------------
#define NMS_CAP 2048

__global__ __launch_bounds__(256) void nms_topk_k(
    const float* __restrict__ logits,
    float* __restrict__ pc_logit, int* __restrict__ pc_ind, int b0)
{
    __shared__ unsigned long long cand[NMS_CAP];
    __shared__ int   cnt;
    __shared__ float rv[4];
    __shared__ int   ri[4];
    __shared__ int   pick;

    const int bc = blockIdx.x;
    const int bl = bc / CN_CLS;
    const int c  = bc % CN_CLS;
    const int bg = b0 + bl;
    const int t  = threadIdx.x;
    const float* L = logits + (size_t)bc * CN_HW;

    if (t == 0) cnt = 0;
    __syncthreads();

    // ---- rolling-stencil scan ----
    {
        const int wv = t >> 6;          // 0..3
        const int ln = t & 63;          // lane
        const int r0 = wv * 32;
        const int c0 = ln * 2;

        float m2_0 = NEG_SENT, m2_1 = NEG_SENT;   // rm3 of row rr-2
        float m1_0 = NEG_SENT, m1_1 = NEG_SENT;   // rm3 of row rr-1
        float pv0 = 0.f, pv1 = 0.f;               // centers of row rr-1

        for (int rr = r0 - 1; rr <= r0 + 32; ++rr) {
            float v0 = NEG_SENT, v1 = NEG_SENT;
            if ((unsigned)rr < (unsigned)CN_H) {
                const float2 vv = *reinterpret_cast<const float2*>(L + (rr << 7) + c0);
                v0 = vv.x; v1 = vv.y;
            }
            float lf = __shfl_up(v1, 1);
            if (ln == 0) lf = NEG_SENT;
            float rt = __shfl_down(v0, 1);
            if (ln == 63) rt = NEG_SENT;
            const float n0 = fmaxf(fmaxf(lf, v0), v1);
            const float n1 = fmaxf(fmaxf(v0, v1), rt);

            const int e = rr - 1;                  // emit row
            if (e >= r0 && e < r0 + 32) {
                const float h0 = fmaxf(fmaxf(m2_0, m1_0), n0);
                const float h1 = fmaxf(fmaxf(m2_1, m1_1), n1);
                if (h0 == pv0) {
                    const int p = (e << 7) + c0;
                    const int slot = atomicAdd(&cnt, 1);
                    if (slot < NMS_CAP)
                        cand[slot] = ((unsigned long long)ordf(pv0) << 32) | (unsigned)(~p);
                }
                if (h1 == pv1) {
                    const int p = (e << 7) + c0 + 1;
                    const int slot = atomicAdd(&cnt, 1);
                    if (slot < NMS_CAP)
                        cand[slot] = ((unsigned long long)ordf(pv1) << 32) | (unsigned)(~p);
                }
            }
            m2_0 = m1_0; m2_1 = m1_1;
            m1_0 = n0;   m1_1 = n1;
            pv0 = v0;    pv1 = v1;
        }
    }
    __syncthreads();
    const int M = cnt;

    if (M >= CN_K && M <= NMS_CAP) {
        int P = 128;
        while (P < M) P <<= 1;
        for (int i = M + t; i < P; i += 256) cand[i] = 0ull;
        __syncthreads();
        for (int k = 2; k <= P; k <<= 1) {
            for (int j = k >> 1; j > 0; j >>= 1) {
                for (int n = t; n < (P >> 1); n += 256) {
                    const int i = ((n & ~(j - 1)) << 1) | (n & (j - 1));
                    const int m = i | j;
                    const unsigned long long a = cand[i], bqq = cand[m];
                    const bool up = ((i & k) == 0);
                    if (up ? (a < bqq) : (a > bqq)) { cand[i] = bqq; cand[m] = a; }
                }
                __syncthreads();
            }
        }
        if (t < CN_K) {
            const unsigned long long key = cand[t];
            const int p = (int)(~(unsigned)key) & 0xFFFF;
            pc_logit[(size_t)bg * 8000 + c * CN_K + t] = unordf((unsigned)(key >> 32));
            pc_ind  [(size_t)bg * 8000 + c * CN_K + t] = p;
        }
    } else {
        // fallback: old-style flags + R4-proven iterative argmax (rare path)
        unsigned long long flags = 0;
        for (int k = 0; k < 64; ++k) {
            const int p   = t + 256 * k;
            const int row = p >> 7, cl = p & 127;
            const float c0v = L[p];
            bool mx = true;
#pragma unroll
            for (int dr = -1; dr <= 1; ++dr)
#pragma unroll
                for (int dc = -1; dc <= 1; ++dc) {
                    if (dr == 0 && dc == 0) continue;
                    int rr2 = row + dr, cc2 = cl + dc;
                    if ((unsigned)rr2 < (unsigned)CN_H && (unsigned)cc2 < (unsigned)CN_W)
                        if (L[(rr2 << 7) + cc2] > c0v) mx = false;
                }
            if (mx) flags |= 1ull << k;
        }
        unsigned long long removed = 0;
        for (int it = 0; it < CN_K; ++it) {
            float bv = -INFINITY;
            int   bi = 0x7fffffff;
            for (int k = 0; k < 64; ++k) {
                if ((removed >> k) & 1) continue;
                const int p = t + 256 * k;
                const float v = ((flags >> k) & 1) ? L[p] : NEG_SENT;
                if (v > bv || (v == bv && p < bi)) { bv = v; bi = p; }
            }
#pragma unroll
            for (int off = 32; off; off >>= 1) {
                float ov = __shfl_down(bv, off);
                int   oi = __shfl_down(bi, off);
                if (ov > bv || (ov == bv && oi < bi)) { bv = ov; bi = oi; }
            }
            const int wid = t >> 6;
            if ((t & 63) == 0) { rv[wid] = bv; ri[wid] = bi; }
            __syncthreads();
            if (t == 0) {
                for (int wv2 = 1; wv2 < 4; ++wv2)
                    if (rv[wv2] > bv || (rv[wv2] == bv && ri[wv2] < bi)) { bv = rv[wv2]; bi = ri[wv2]; }
                pc_logit[(size_t)bg * 8000 + c * CN_K + it] = bv;
                pc_ind  [(size_t)bg * 8000 + c * CN_K + it] = bi;
                pick = bi;
            }
            __syncthreads();
            const int pk = pick;
            if ((pk & 255) == t) removed |= 1ull << (pk >> 8);
            __syncthreads();
        }
    }
}

// ---------------------------------------------------------------------------
// Global top-100 via 80-way merge-pop (proven R10/R11).
// ---------------------------------------------------------------------------
__global__ __launch_bounds__(256) void global_topk_k(
    const float* __restrict__ pc_logit, const int* __restrict__ pc_ind,
    int* __restrict__ sel)
{
    constexpr int N = CN_CLS * CN_K;           // 8000
    __shared__ unsigned long long keys[N];     // 64 KB
    __shared__ unsigned long long heads[128];
    __shared__ int rcs[CN_CLS];

    const int b = blockIdx.x;
    const int t = threadIdx.x;

    for (int n = t; n < N; n += 256) {
        const float v = pc_logit[(size_t)b * N + n];
        keys[n] = ((unsigned long long)ordf(v) << 32) | (unsigned)(~n);
    }
    if (t >= CN_CLS && t < 128) heads[t] = 0ull;
    __syncthreads();
    if (t < CN_CLS) { heads[t] = keys[t * CN_K]; rcs[t] = 1; }
    __syncthreads();

    for (int it = 0; it < CN_K; ++it) {
        if (t < 64) {
            unsigned long long k0 = heads[t];
            unsigned long long k1 = heads[t + 64];
            unsigned long long bk = (k0 >= k1) ? k0 : k1;
#pragma unroll
            for (int off = 32; off; off >>= 1) {
                unsigned long long ok = __shfl_down(bk, off);
                if (ok > bk) bk = ok;
            }
            if (t == 0) {
                const int flat = (int)(~(unsigned)bk);
                const int c    = flat / CN_K;
                sel[((size_t)b * CN_K + it) * 3 + 0] = pc_ind[(size_t)b * N + flat];
                sel[((size_t)b * CN_K + it) * 3 + 1] = c;
                sel[((size_t)b * CN_K + it) * 3 + 2] = (int)(unsigned)(bk >> 32);
                const int rc = rcs[c]++;
                heads[c] = (rc < CN_K) ? keys[c * CN_K + rc] : 0ull;
            }
        }
        __syncthreads();
    }
}

// ---------------------------------------------------------------------------
// Sparse wh + bbox assembly (proven R8-R11): one block per (b, k).
// ---------------------------------------------------------------------------
__global__ __launch_bounds__(256) void whbbox_k(
    const float* __restrict__ x,
    const float* __restrict__ w1, const float* __restrict__ b1,
    const float* __restrict__ w2, const float* __restrict__ b2,
    const float* __restrict__ w3, const float* __restrict__ b3,
    const int* __restrict__ sel, float* __restrict__ out)
{
    __shared__ float xw[64][25];
    __shared__ float g1s[9][64];
    __shared__ float g2s[64];
    __shared__ float whs[4];

    const int bk = blockIdx.x;
    const int b  = bk / CN_K;
    const int k  = bk % CN_K;
    const int t  = threadIdx.x;

    const int   ind   = sel[((size_t)b * CN_K + k) * 3 + 0];
    const int   cls   = sel[((size_t)b * CN_K + k) * 3 + 1];
    const float lg    = unordf((unsigned)sel[((size_t)b * CN_K + k) * 3 + 2]);
    const int   py = ind >> 7, px = ind & 127;

    for (int e = t; e < 64 * 25; e += 256) {
        const int c = e / 25, r = e % 25;
        const int qy = py + r / 5 - 2, qx = px + r % 5 - 2;
        float v = 0.f;
        if ((unsigned)qy < (unsigned)CN_H && (unsigned)qx < (unsigned)CN_W)
            v = x[(((size_t)b * 64 + c) * CN_H + qy) * CN_W + qx];
        xw[c][r] = v;
    }
    __syncthreads();

    for (int e = t; e < 576; e += 256) {
        const int ci = e & 63, qp = e >> 6;
        const int qdy = qp / 3 - 1, qdx = qp % 3 - 1;
        const int qy = py + qdy, qx = px + qdx;
        float s = 0.f;
        if ((unsigned)qy < (unsigned)CN_H && (unsigned)qx < (unsigned)CN_W) {
            const float* wp = w1 + (size_t)ci * 64 * 9;
            for (int cj = 0; cj < 64; ++cj) {
#pragma unroll
                for (int jh = 0; jh < 3; ++jh)
#pragma unroll
                    for (int jw = 0; jw < 3; ++jw)
                        s = fmaf(xw[cj][(qdy + jh + 1) * 5 + (qdx + jw + 1)],
                                 wp[cj * 9 + jh * 3 + jw], s);
            }
            s += b1[ci];
            s = s > 0.f ? s : 0.f;
        }
        g1s[qp][ci] = s;
    }
    __syncthreads();

    if (t < 64) {
        const int oc = t;
        const float* wp = w2 + (size_t)oc * 64 * 9;
        float s = 0.f;
        for (int ci = 0; ci < 64; ++ci) {
#pragma unroll
            for (int kh = 0; kh < 3; ++kh)
#pragma unroll
                for (int kw = 0; kw < 3; ++kw)
                    s = fmaf(g1s[kh * 3 + kw][ci], wp[ci * 9 + kh * 3 + kw], s);
        }
        s += b2[oc];
        g2s[oc] = s > 0.f ? s : 0.f;
    }
    __syncthreads();

    if (t < 4) {
        float s = 0.f;
        const float* wp = w3 + (size_t)t * 64;
        for (int oc = 0; oc < 64; ++oc) s = fmaf(g2s[oc], wp[oc], s);
        s += b3[t];
        s = s > 0.f ? s : 0.f;
        whs[t] = s * 16.0f;
    }
    __syncthreads();

    if (t == 0) {
        const float score = (float)(1.0 / (1.0 + exp(-(double)lg)));
        const float ys = (float)py * 4.0f;
        const float xs = (float)px * 4.0f;
        float* row = out + ((size_t)b * CN_K + k) * 6;
        row[0] = xs - whs[0];
        row[1] = ys - whs[1];
        row[2] = xs + whs[2];
        row[3] = ys + whs[3];
        row[4] = score;
        row[5] = (float)cls;
        out[CN_B * CN_K * 6 + b * CN_K + k] = (score > 0.01f) ? 1.0f : 0.0f;
    }
}

// ---------------------------------------------------------------------------
extern "C" void kernel_launch(void* const* d_in, const int* in_sizes, int n_in,
                              void* d_out, int out_size, void* d_ws, size_t ws_size,
                              hipStream_t stream)
{
    (void)in_sizes; (void)n_in; (void)out_size;

    const float* x      = (const float*)d_in[0];
    const float* cls_w1 = (const float*)d_in[1];
    const float* cls_b1 = (const float*)d_in[2];
    const float* cls_w2 = (const float*)d_in[3];
    const float* cls_b2 = (const float*)d_in[4];
    const float* cls_w3 = (const float*)d_in[5];
    const float* cls_b3 = (const float*)d_in[6];
    const float* wh_w1  = (const float*)d_in[7];
    const float* wh_b1  = (const float*)d_in[8];
    const float* wh_w2  = (const float*)d_in[9];
    const float* wh_b2  = (const float*)d_in[10];
    const float* wh_w3  = (const float*)d_in[11];
    const float* wh_b3  = (const float*)d_in[12];
    float* out = (float*)d_out;

    const size_t SZ_PCS = 512000u, SZ_PCI = 512000u;
    const size_t SZ_WT1 = 294912u, SZ_WT2 = 589824u;
    const size_t SZ_WTC = 81920u;
    const size_t SZ_SEL = 19200u;
    const size_t PERS = SZ_PCS + SZ_PCI + SZ_WT1 + SZ_WT2 + SZ_WTC + SZ_SEL;
    const size_t PER_IMG = 16777216u;

    int Bc = 1;
    if (ws_size > PERS) {
        size_t m = (ws_size - PERS) / PER_IMG;
        Bc = (int)(m < 1 ? 1 : (m > 16 ? 16 : m));
    }

    char* ws = (char*)d_ws;
    float*  pc_s = (float*)ws;
    int*    pc_i = (int*)(ws + SZ_PCS);
    float*  wt1  = (float*)(ws + SZ_PCS + SZ_PCI);
    float*  wt2  = (float*)(ws + SZ_PCS + SZ_PCI + SZ_WT1);
    double* wtc  = (double*)(ws + SZ_PCS + SZ_PCI + SZ_WT1 + SZ_WT2);
    int*    sel  = (int*)(ws + SZ_PCS + SZ_PCI + SZ_WT1 + SZ_WT2 + SZ_WTC);
    char*   regA = ws + PERS;
    char*   regB = regA + (size_t)Bc * 8388608u;

    dim3 blk(256);

    wtr_k<<<dim3((64 * 9 * 128 + 255) / 256), blk, 0, stream>>>(cls_w1, wt1, 64, 128);
    wtr_k<<<dim3((128 * 9 * 128 + 255) / 256), blk, 0, stream>>>(cls_w2, wt2, 128, 128);
    wtr1x1_k<<<dim3((128 * CN_CLS + 255) / 256), blk, 0, stream>>>(cls_w3, wtc);

    for (int b0 = 0; b0 < CN_B; b0 += Bc) {
        const int Bcur = (CN_B - b0 < Bc) ? (CN_B - b0) : Bc;
        const float* xc = x + (size_t)b0 * 64 * CN_HW;
        float* h1     = (float*)regA;
        float* h2     = (float*)regB;
        float* logits = (float*)regA;

        conv_a_k<<<dim3(Bcur * 16 * 8), blk, 0, stream>>>(xc, wt1, cls_b1, h1, 128);
        conv_b_k<<<dim3(Bcur * 16 * 8), blk, 0, stream>>>(h1, wt2, cls_b2, h2, 128);
        conv1x1_cls_k<<<dim3(Bcur * 64 * 5), blk, 0, stream>>>(h2, wtc, cls_b3, logits);
        nms_topk_k<<<dim3(Bcur * CN_CLS), blk, 0, stream>>>(logits, pc_s, pc_i, b0);
    }

    global_topk_k<<<dim3(CN_B), blk, 0, stream>>>(pc_s, pc_i, sel);
    whbbox_k<<<dim3(CN_B * CN_K), blk, 0, stream>>>(
        x, wh_w1, wh_b1, wh_w2, wh_b2, wh_w3, wh_b3, sel, out);
}

// Round 14
// 2300.352 us; speedup vs baseline: 3.2199x; 1.0150x over previous
//
#include <hip/hip_runtime.h>
#include <cmath>
#include <cstdint>
#include <cfloat>

// ---------------------------------------------------------------------------
// CenterNet head, MI355X. Round 14: packed-f32 conv FMAs (v_pk_fma_f32 via
// __builtin_elementwise_fma on float2 ext-vectors; 2 IEEE FMAs per issue).
// Everything else frozen R13 (2335us, absmax 0.0).
// Numerics contract (proven R3-R13, absmax 0.0):
//   - cls 3x3 convs: f32 fmaf chains, EXACT per-output order (ci asc, kh, kw).
//     pk_fma halves are independent IEEE fmas -> chains bit-identical.
//   - cls 1x1: f64 accum (ci 0..127) -> correctly-rounded f32 logits.
//   - Selection on f32 logits, ties by lowest index (u64 key = ordf<<32 | ~i).
//   - NMS flag: max3x3(incl center)==center (rolling stencil, R13-proven).
//   - wh: sparse f32 recompute at selected pixels (tolerance 10.08).
// ---------------------------------------------------------------------------

#define CN_B   16
#define CN_H   128
#define CN_W   128
#define CN_HW  16384
#define CN_CLS 80
#define CN_K   100
#define NEG_SENT (-3.402823466e+38f)

typedef float v2f __attribute__((ext_vector_type(2)));

__device__ __forceinline__ unsigned ordf(float v) {
    unsigned b = __float_as_uint(v);
    return (b >> 31) ? ~b : (b | 0x80000000u);
}
__device__ __forceinline__ float unordf(unsigned o) {
    return __uint_as_float((o >> 31) ? (o & 0x7fffffffu) : ~o);
}

// Bijective chunked XCD transform (m204): XCD x gets a contiguous chunk.
__device__ __forceinline__ int xcd_swz(int bid, int nwg) {
    const int q = nwg >> 3, r = nwg & 7;
    const int x = bid & 7, off = bid >> 3;
    return (x < r ? x * (q + 1) : r * (q + 1) + (x - r) * q) + off;
}

// ---------------------------------------------------------------------------
// 3x3 weight transpose (bit-copy): wt[(ci*9+tap)*CO + co] = w[co][ci][tap].
// ---------------------------------------------------------------------------
__global__ __launch_bounds__(256) void wtr_k(
    const float* __restrict__ w, float* __restrict__ wt, int CI, int CO)
{
    const int e = blockIdx.x * 256 + threadIdx.x;
    const int n = CI * 9 * CO;
    if (e < n) {
        const int co = e % CO;
        const int rest = e / CO;            // ci*9 + tap
        wt[e] = w[(size_t)co * CI * 9 + rest];
    }
}

// 1x1 weight transpose to f64 (exact): wt[ci*80 + o] = (double)w[o*128 + ci].
__global__ __launch_bounds__(256) void wtr1x1_k(
    const float* __restrict__ w, double* __restrict__ wt)
{
    const int e = blockIdx.x * 256 + threadIdx.x;
    if (e < 128 * CN_CLS) {
        const int ci = e / CN_CLS, o = e % CN_CLS;
        wt[e] = (double)w[(size_t)o * 128 + ci];
    }
}

// ---------------------------------------------------------------------------
// f32 3x3 conv, pad 1, bias + ReLU. R11/R13 structure (tile 8 rows x 128 cols
// x 16 oc, CC=4, SGPR weights, contiguous-row px map) with PACKED accumulators:
// acc2[j][op] holds outputs (2op, 2op+1); one v_pk_fma_f32 = 2 FMAs/issue.
// Per-(row,o) fmaf chain: (ci0 asc, cc, kh, kw) — IDENTICAL bits to R3-R13.
// grid.x = Bc * 16 * (CO/16), co-tile fastest + XCD swizzle.
// ---------------------------------------------------------------------------
template<int CI>
__device__ __forceinline__ void conv3x3_body(
    const float* __restrict__ in, const float* __restrict__ wt,
    const float* __restrict__ bias, float* __restrict__ out, int CO)
{
    constexpr int CC = 4;
    const int wg  = xcd_swz(blockIdx.x, gridDim.x);
    const int cob = CO >> 4;
    const int co0 = (wg % cob) * 16;
    const int tmp = wg / cob;
    const int h0  = (tmp & 15) * 8;
    const int b   = tmp >> 4;

    __shared__ float lin[CC][10][132];   // 21.1 KB

    const int t   = threadIdx.x;
    const int col = t & 127;
    const int r2  = t >> 7;              // 0..1: rows r2*4 .. r2*4+3
    const int g   = t >> 6;              // staging cc 0..3
    const int ln  = t & 63;

    v2f acc2[4][8];
#pragma unroll
    for (int j = 0; j < 4; ++j)
#pragma unroll
        for (int op = 0; op < 8; ++op) acc2[j][op] = (v2f){0.f, 0.f};

    for (int ci0 = 0; ci0 < CI; ci0 += CC) {
        // ---- input staging (proven R5/R8 form) ----
        {
            const float* base = in + (((size_t)b * CI + ci0 + g) * CN_H) * CN_W;
#pragma unroll
            for (int rr = 0; rr < 10; ++rr) {
                const int srow = h0 - 1 + rr;
                const bool rok = (unsigned)srow < (unsigned)CN_H;
                const float* src = base + srow * CN_W;
#pragma unroll
                for (int q = 0; q < 2; ++q) {
                    const int lidx = ln + 64 * q;
                    const int scol = lidx - 1;
                    lin[g][rr][lidx] =
                        (rok && (unsigned)scol < (unsigned)CN_W) ? src[scol] : 0.f;
                }
                if (ln < 2) {
                    const int lidx = 128 + ln;
                    const int scol = lidx - 1;
                    lin[g][rr][lidx] =
                        (rok && (unsigned)scol < (unsigned)CN_W) ? src[scol] : 0.f;
                }
            }
        }
        __syncthreads();
        // ---- compute: 18 LDS reads/cc, SGPR weight pairs, pk FMAs ----
        for (int cc = 0; cc < CC; ++cc) {
            float rb[6][3];
#pragma unroll
            for (int rr = 0; rr < 6; ++rr) {
                const int lr = r2 * 4 + rr;
                rb[rr][0] = lin[cc][lr][col + 0];
                rb[rr][1] = lin[cc][lr][col + 1];
                rb[rr][2] = lin[cc][lr][col + 2];
            }
#pragma unroll
            for (int kh = 0; kh < 3; ++kh) {
#pragma unroll
                for (int kw = 0; kw < 3; ++kw) {
                    const float* wr =
                        wt + (size_t)((ci0 + cc) * 9 + kh * 3 + kw) * CO + co0;
                    const v2f vv0 = (v2f){rb[0 + kh][kw], rb[0 + kh][kw]};
                    const v2f vv1 = (v2f){rb[1 + kh][kw], rb[1 + kh][kw]};
                    const v2f vv2 = (v2f){rb[2 + kh][kw], rb[2 + kh][kw]};
                    const v2f vv3 = (v2f){rb[3 + kh][kw], rb[3 + kh][kw]};
#pragma unroll
                    for (int op = 0; op < 8; ++op) {
                        const v2f ww = *reinterpret_cast<const v2f*>(wr + 2 * op);
                        acc2[0][op] = __builtin_elementwise_fma(vv0, ww, acc2[0][op]);
                        acc2[1][op] = __builtin_elementwise_fma(vv1, ww, acc2[1][op]);
                        acc2[2][op] = __builtin_elementwise_fma(vv2, ww, acc2[2][op]);
                        acc2[3][op] = __builtin_elementwise_fma(vv3, ww, acc2[3][op]);
                    }
                }
            }
        }
        __syncthreads();
    }

#pragma unroll
    for (int j = 0; j < 4; ++j) {
        const int h = h0 + r2 * 4 + j;
#pragma unroll
        for (int op = 0; op < 8; ++op) {
            float v0 = acc2[j][op].x + bias[co0 + 2 * op + 0];
            float v1 = acc2[j][op].y + bias[co0 + 2 * op + 1];
            v0 = v0 > 0.f ? v0 : 0.f;
            v1 = v1 > 0.f ? v1 : 0.f;
            out[(((size_t)b * CO + co0 + 2 * op + 0) * CN_H + h) * CN_W + col] = v0;
            out[(((size_t)b * CO + co0 + 2 * op + 1) * CN_H + h) * CN_W + col] = v1;
        }
    }
}

__global__ __launch_bounds__(256) void conv_a_k(   // cls1: 64 -> 128
    const float* __restrict__ in, const float* __restrict__ wt,
    const float* __restrict__ bias, float* __restrict__ out, int CO)
{ conv3x3_body<64>(in, wt, bias, out, CO); }

__global__ __launch_bounds__(256) void conv_b_k(   // cls2: 128 -> 128
    const float* __restrict__ in, const float* __restrict__ wt,
    const float* __restrict__ bias, float* __restrict__ out, int CO)
{ conv3x3_body<128>(in, wt, bias, out, CO); }

// ---------------------------------------------------------------------------
// 1x1 cls: 128 -> 80, f64 accumulate, SGPR weight path (proven R10-R13).
// ---------------------------------------------------------------------------
__global__ __launch_bounds__(256) void conv1x1_cls_k(
    const float* __restrict__ h2, const double* __restrict__ wt,
    const float* __restrict__ bias, float* __restrict__ logits)
{
    constexpr int CI = 128;
    const int wg = xcd_swz(blockIdx.x, gridDim.x);
    const int og = wg % 5;
    const int pb = wg / 5;
    const int b  = pb / 64;
    const int p  = (pb % 64) * 256 + threadIdx.x;
    const int o0 = og * 16;

    double acc[16];
#pragma unroll
    for (int o = 0; o < 16; ++o) acc[o] = 0.0;

    for (int ci = 0; ci < CI; ++ci) {
        const double v = (double)h2[((size_t)b * CI + ci) * CN_HW + p];
        const double* wr = wt + (size_t)ci * CN_CLS + o0;   // wave-uniform
#pragma unroll
        for (int o = 0; o < 16; ++o) acc[o] = fma(v, wr[o], acc[o]);
    }
#pragma unroll
    for (int o = 0; o < 16; ++o)
        logits[((size_t)b * CN_CLS + o0 + o) * CN_HW + p] =
            (float)(acc[o] + (double)bias[o0 + o]);
}

// ---------------------------------------------------------------------------
// NMS + per-class top-100 (R13-proven rolling stencil + bitonic + fallback).
// ---------------------------------------------------------------------------
#define NMS_CAP 2048

__global__ __launch_bounds__(256) void nms_topk_k(
    const float* __restrict__ logits,
    float* __restrict__ pc_logit, int* __restrict__ pc_ind, int b0)
{
    __shared__ unsigned long long cand[NMS_CAP];
    __shared__ int   cnt;
    __shared__ float rv[4];
    __shared__ int   ri[4];
    __shared__ int   pick;

    const int bc = blockIdx.x;
    const int bl = bc / CN_CLS;
    const int c  = bc % CN_CLS;
    const int bg = b0 + bl;
    const int t  = threadIdx.x;
    const float* L = logits + (size_t)bc * CN_HW;

    if (t == 0) cnt = 0;
    __syncthreads();

    // ---- rolling-stencil scan ----
    {
        const int wv = t >> 6;
        const int ln = t & 63;
        const int r0 = wv * 32;
        const int c0 = ln * 2;

        float m2_0 = NEG_SENT, m2_1 = NEG_SENT;
        float m1_0 = NEG_SENT, m1_1 = NEG_SENT;
        float pv0 = 0.f, pv1 = 0.f;

        for (int rr = r0 - 1; rr <= r0 + 32; ++rr) {
            float v0 = NEG_SENT, v1 = NEG_SENT;
            if ((unsigned)rr < (unsigned)CN_H) {
                const float2 vv = *reinterpret_cast<const float2*>(L + (rr << 7) + c0);
                v0 = vv.x; v1 = vv.y;
            }
            float lf = __shfl_up(v1, 1);
            if (ln == 0) lf = NEG_SENT;
            float rt = __shfl_down(v0, 1);
            if (ln == 63) rt = NEG_SENT;
            const float n0 = fmaxf(fmaxf(lf, v0), v1);
            const float n1 = fmaxf(fmaxf(v0, v1), rt);

            const int e = rr - 1;
            if (e >= r0 && e < r0 + 32) {
                const float h0 = fmaxf(fmaxf(m2_0, m1_0), n0);
                const float h1 = fmaxf(fmaxf(m2_1, m1_1), n1);
                if (h0 == pv0) {
                    const int p = (e << 7) + c0;
                    const int slot = atomicAdd(&cnt, 1);
                    if (slot < NMS_CAP)
                        cand[slot] = ((unsigned long long)ordf(pv0) << 32) | (unsigned)(~p);
                }
                if (h1 == pv1) {
                    const int p = (e << 7) + c0 + 1;
                    const int slot = atomicAdd(&cnt, 1);
                    if (slot < NMS_CAP)
                        cand[slot] = ((unsigned long long)ordf(pv1) << 32) | (unsigned)(~p);
                }
            }
            m2_0 = m1_0; m2_1 = m1_1;
            m1_0 = n0;   m1_1 = n1;
            pv0 = v0;    pv1 = v1;
        }
    }
    __syncthreads();
    const int M = cnt;

    if (M >= CN_K && M <= NMS_CAP) {
        int P = 128;
        while (P < M) P <<= 1;
        for (int i = M + t; i < P; i += 256) cand[i] = 0ull;
        __syncthreads();
        for (int k = 2; k <= P; k <<= 1) {
            for (int j = k >> 1; j > 0; j >>= 1) {
                for (int n = t; n < (P >> 1); n += 256) {
                    const int i = ((n & ~(j - 1)) << 1) | (n & (j - 1));
                    const int m = i | j;
                    const unsigned long long a = cand[i], bqq = cand[m];
                    const bool up = ((i & k) == 0);
                    if (up ? (a < bqq) : (a > bqq)) { cand[i] = bqq; cand[m] = a; }
                }
                __syncthreads();
            }
        }
        if (t < CN_K) {
            const unsigned long long key = cand[t];
            const int p = (int)(~(unsigned)key) & 0xFFFF;
            pc_logit[(size_t)bg * 8000 + c * CN_K + t] = unordf((unsigned)(key >> 32));
            pc_ind  [(size_t)bg * 8000 + c * CN_K + t] = p;
        }
    } else {
        // fallback: old-style flags + R4-proven iterative argmax (rare path)
        unsigned long long flags = 0;
        for (int k = 0; k < 64; ++k) {
            const int p   = t + 256 * k;
            const int row = p >> 7, cl = p & 127;
            const float c0v = L[p];
            bool mx = true;
#pragma unroll
            for (int dr = -1; dr <= 1; ++dr)
#pragma unroll
                for (int dc = -1; dc <= 1; ++dc) {
                    if (dr == 0 && dc == 0) continue;
                    int rr2 = row + dr, cc2 = cl + dc;
                    if ((unsigned)rr2 < (unsigned)CN_H && (unsigned)cc2 < (unsigned)CN_W)
                        if (L[(rr2 << 7) + cc2] > c0v) mx = false;
                }
            if (mx) flags |= 1ull << k;
        }
        unsigned long long removed = 0;
        for (int it = 0; it < CN_K; ++it) {
            float bv = -INFINITY;
            int   bi = 0x7fffffff;
            for (int k = 0; k < 64; ++k) {
                if ((removed >> k) & 1) continue;
                const int p = t + 256 * k;
                const float v = ((flags >> k) & 1) ? L[p] : NEG_SENT;
                if (v > bv || (v == bv && p < bi)) { bv = v; bi = p; }
            }
#pragma unroll
            for (int off = 32; off; off >>= 1) {
                float ov = __shfl_down(bv, off);
                int   oi = __shfl_down(bi, off);
                if (ov > bv || (ov == bv && oi < bi)) { bv = ov; bi = oi; }
            }
            const int wid = t >> 6;
            if ((t & 63) == 0) { rv[wid] = bv; ri[wid] = bi; }
            __syncthreads();
            if (t == 0) {
                for (int wv2 = 1; wv2 < 4; ++wv2)
                    if (rv[wv2] > bv || (rv[wv2] == bv && ri[wv2] < bi)) { bv = rv[wv2]; bi = ri[wv2]; }
                pc_logit[(size_t)bg * 8000 + c * CN_K + it] = bv;
                pc_ind  [(size_t)bg * 8000 + c * CN_K + it] = bi;
                pick = bi;
            }
            __syncthreads();
            const int pk = pick;
            if ((pk & 255) == t) removed |= 1ull << (pk >> 8);
            __syncthreads();
        }
    }
}

// ---------------------------------------------------------------------------
// Global top-100 via 80-way merge-pop (proven R10-R13).
// ---------------------------------------------------------------------------
__global__ __launch_bounds__(256) void global_topk_k(
    const float* __restrict__ pc_logit, const int* __restrict__ pc_ind,
    int* __restrict__ sel)
{
    constexpr int N = CN_CLS * CN_K;           // 8000
    __shared__ unsigned long long keys[N];     // 64 KB
    __shared__ unsigned long long heads[128];
    __shared__ int rcs[CN_CLS];

    const int b = blockIdx.x;
    const int t = threadIdx.x;

    for (int n = t; n < N; n += 256) {
        const float v = pc_logit[(size_t)b * N + n];
        keys[n] = ((unsigned long long)ordf(v) << 32) | (unsigned)(~n);
    }
    if (t >= CN_CLS && t < 128) heads[t] = 0ull;
    __syncthreads();
    if (t < CN_CLS) { heads[t] = keys[t * CN_K]; rcs[t] = 1; }
    __syncthreads();

    for (int it = 0; it < CN_K; ++it) {
        if (t < 64) {
            unsigned long long k0 = heads[t];
            unsigned long long k1 = heads[t + 64];
            unsigned long long bk = (k0 >= k1) ? k0 : k1;
#pragma unroll
            for (int off = 32; off; off >>= 1) {
                unsigned long long ok = __shfl_down(bk, off);
                if (ok > bk) bk = ok;
            }
            if (t == 0) {
                const int flat = (int)(~(unsigned)bk);
                const int c    = flat / CN_K;
                sel[((size_t)b * CN_K + it) * 3 + 0] = pc_ind[(size_t)b * N + flat];
                sel[((size_t)b * CN_K + it) * 3 + 1] = c;
                sel[((size_t)b * CN_K + it) * 3 + 2] = (int)(unsigned)(bk >> 32);
                const int rc = rcs[c]++;
                heads[c] = (rc < CN_K) ? keys[c * CN_K + rc] : 0ull;
            }
        }
        __syncthreads();
    }
}

// ---------------------------------------------------------------------------
// Sparse wh + bbox assembly (proven R8-R13): one block per (b, k).
// ---------------------------------------------------------------------------
__global__ __launch_bounds__(256) void whbbox_k(
    const float* __restrict__ x,
    const float* __restrict__ w1, const float* __restrict__ b1,
    const float* __restrict__ w2, const float* __restrict__ b2,
    const float* __restrict__ w3, const float* __restrict__ b3,
    const int* __restrict__ sel, float* __restrict__ out)
{
    __shared__ float xw[64][25];
    __shared__ float g1s[9][64];
    __shared__ float g2s[64];
    __shared__ float whs[4];

    const int bk = blockIdx.x;
    const int b  = bk / CN_K;
    const int k  = bk % CN_K;
    const int t  = threadIdx.x;

    const int   ind   = sel[((size_t)b * CN_K + k) * 3 + 0];
    const int   cls   = sel[((size_t)b * CN_K + k) * 3 + 1];
    const float lg    = unordf((unsigned)sel[((size_t)b * CN_K + k) * 3 + 2]);
    const int   py = ind >> 7, px = ind & 127;

    for (int e = t; e < 64 * 25; e += 256) {
        const int c = e / 25, r = e % 25;
        const int qy = py + r / 5 - 2, qx = px + r % 5 - 2;
        float v = 0.f;
        if ((unsigned)qy < (unsigned)CN_H && (unsigned)qx < (unsigned)CN_W)
            v = x[(((size_t)b * 64 + c) * CN_H + qy) * CN_W + qx];
        xw[c][r] = v;
    }
    __syncthreads();

    for (int e = t; e < 576; e += 256) {
        const int ci = e & 63, qp = e >> 6;
        const int qdy = qp / 3 - 1, qdx = qp % 3 - 1;
        const int qy = py + qdy, qx = px + qdx;
        float s = 0.f;
        if ((unsigned)qy < (unsigned)CN_H && (unsigned)qx < (unsigned)CN_W) {
            const float* wp = w1 + (size_t)ci * 64 * 9;
            for (int cj = 0; cj < 64; ++cj) {
#pragma unroll
                for (int jh = 0; jh < 3; ++jh)
#pragma unroll
                    for (int jw = 0; jw < 3; ++jw)
                        s = fmaf(xw[cj][(qdy + jh + 1) * 5 + (qdx + jw + 1)],
                                 wp[cj * 9 + jh * 3 + jw], s);
            }
            s += b1[ci];
            s = s > 0.f ? s : 0.f;
        }
        g1s[qp][ci] = s;
    }
    __syncthreads();

    if (t < 64) {
        const int oc = t;
        const float* wp = w2 + (size_t)oc * 64 * 9;
        float s = 0.f;
        for (int ci = 0; ci < 64; ++ci) {
#pragma unroll
            for (int kh = 0; kh < 3; ++kh)
#pragma unroll
                for (int kw = 0; kw < 3; ++kw)
                    s = fmaf(g1s[kh * 3 + kw][ci], wp[ci * 9 + kh * 3 + kw], s);
        }
        s += b2[oc];
        g2s[oc] = s > 0.f ? s : 0.f;
    }
    __syncthreads();

    if (t < 4) {
        float s = 0.f;
        const float* wp = w3 + (size_t)t * 64;
        for (int oc = 0; oc < 64; ++oc) s = fmaf(g2s[oc], wp[oc], s);
        s += b3[t];
        s = s > 0.f ? s : 0.f;
        whs[t] = s * 16.0f;
    }
    __syncthreads();

    if (t == 0) {
        const float score = (float)(1.0 / (1.0 + exp(-(double)lg)));
        const float ys = (float)py * 4.0f;
        const float xs = (float)px * 4.0f;
        float* row = out + ((size_t)b * CN_K + k) * 6;
        row[0] = xs - whs[0];
        row[1] = ys - whs[1];
        row[2] = xs + whs[2];
        row[3] = ys + whs[3];
        row[4] = score;
        row[5] = (float)cls;
        out[CN_B * CN_K * 6 + b * CN_K + k] = (score > 0.01f) ? 1.0f : 0.0f;
    }
}

// ---------------------------------------------------------------------------
extern "C" void kernel_launch(void* const* d_in, const int* in_sizes, int n_in,
                              void* d_out, int out_size, void* d_ws, size_t ws_size,
                              hipStream_t stream)
{
    (void)in_sizes; (void)n_in; (void)out_size;

    const float* x      = (const float*)d_in[0];
    const float* cls_w1 = (const float*)d_in[1];
    const float* cls_b1 = (const float*)d_in[2];
    const float* cls_w2 = (const float*)d_in[3];
    const float* cls_b2 = (const float*)d_in[4];
    const float* cls_w3 = (const float*)d_in[5];
    const float* cls_b3 = (const float*)d_in[6];
    const float* wh_w1  = (const float*)d_in[7];
    const float* wh_b1  = (const float*)d_in[8];
    const float* wh_w2  = (const float*)d_in[9];
    const float* wh_b2  = (const float*)d_in[10];
    const float* wh_w3  = (const float*)d_in[11];
    const float* wh_b3  = (const float*)d_in[12];
    float* out = (float*)d_out;

    const size_t SZ_PCS = 512000u, SZ_PCI = 512000u;
    const size_t SZ_WT1 = 294912u, SZ_WT2 = 589824u;
    const size_t SZ_WTC = 81920u;
    const size_t SZ_SEL = 19200u;
    const size_t PERS = SZ_PCS + SZ_PCI + SZ_WT1 + SZ_WT2 + SZ_WTC + SZ_SEL;
    const size_t PER_IMG = 16777216u;

    int Bc = 1;
    if (ws_size > PERS) {
        size_t m = (ws_size - PERS) / PER_IMG;
        Bc = (int)(m < 1 ? 1 : (m > 16 ? 16 : m));
    }

    char* ws = (char*)d_ws;
    float*  pc_s = (float*)ws;
    int*    pc_i = (int*)(ws + SZ_PCS);
    float*  wt1  = (float*)(ws + SZ_PCS + SZ_PCI);
    float*  wt2  = (float*)(ws + SZ_PCS + SZ_PCI + SZ_WT1);
    double* wtc  = (double*)(ws + SZ_PCS + SZ_PCI + SZ_WT1 + SZ_WT2);
    int*    sel  = (int*)(ws + SZ_PCS + SZ_PCI + SZ_WT1 + SZ_WT2 + SZ_WTC);
    char*   regA = ws + PERS;
    char*   regB = regA + (size_t)Bc * 8388608u;

    dim3 blk(256);

    wtr_k<<<dim3((64 * 9 * 128 + 255) / 256), blk, 0, stream>>>(cls_w1, wt1, 64, 128);
    wtr_k<<<dim3((128 * 9 * 128 + 255) / 256), blk, 0, stream>>>(cls_w2, wt2, 128, 128);
    wtr1x1_k<<<dim3((128 * CN_CLS + 255) / 256), blk, 0, stream>>>(cls_w3, wtc);

    for (int b0 = 0; b0 < CN_B; b0 += Bc) {
        const int Bcur = (CN_B - b0 < Bc) ? (CN_B - b0) : Bc;
        const float* xc = x + (size_t)b0 * 64 * CN_HW;
        float* h1     = (float*)regA;
        float* h2     = (float*)regB;
        float* logits = (float*)regA;

        conv_a_k<<<dim3(Bcur * 16 * 8), blk, 0, stream>>>(xc, wt1, cls_b1, h1, 128);
        conv_b_k<<<dim3(Bcur * 16 * 8), blk, 0, stream>>>(h1, wt2, cls_b2, h2, 128);
        conv1x1_cls_k<<<dim3(Bcur * 64 * 5), blk, 0, stream>>>(h2, wtc, cls_b3, logits);
        nms_topk_k<<<dim3(Bcur * CN_CLS), blk, 0, stream>>>(logits, pc_s, pc_i, b0);
    }

    global_topk_k<<<dim3(CN_B), blk, 0, stream>>>(pc_s, pc_i, sel);
    whbbox_k<<<dim3(CN_B * CN_K), blk, 0, stream>>>(
        x, wh_w1, wh_b1, wh_w2, wh_b2, wh_w3, wh_b3, sel, out);
}